// Round 3
// baseline (589.174 us; speedup 1.0000x reference)
//
#include <hip/hip_runtime.h>
#include <hip/hip_bf16.h>
#include <stdint.h>
#include <stddef.h>

// Problem dims
#define Bn 128
#define Sn 1000
#define SP 1024   // padded S
#define Hn 256

typedef __bf16 bf16;
typedef __bf16 bf16x8 __attribute__((ext_vector_type(8)));
typedef __bf16 bf16x4 __attribute__((ext_vector_type(4)));
typedef __bf16 bf16x2 __attribute__((ext_vector_type(2)));
typedef float  f32x4  __attribute__((ext_vector_type(4)));

typedef __attribute__((address_space(1))) const unsigned int* gas1;
typedef __attribute__((address_space(3))) unsigned int* las3;

__device__ __forceinline__ float fast_tanh(float x){
  return 1.0f - 2.0f / (__expf(2.0f * x) + 1.0f);
}
__device__ __forceinline__ float fast_sigmoid(float x){
  return 1.0f / (1.0f + __expf(-x));
}
__device__ __forceinline__ float dot4(float4 a, float4 b){
  return a.x*b.x + a.y*b.y + a.z*b.z + a.w*b.w;
}
__device__ __forceinline__ float wave_reduce(float v){
  #pragma unroll
  for (int o=1;o<64;o<<=1) v += __shfl_xor(v, o);
  return v;
}

// ---------------------------------------------------------------------------
// K0a: static fp32 -> bf16, padded to (B,1024,H); pad rows are zero.
__global__ void k0a_convert(const float* __restrict__ stat, bf16* __restrict__ Abf){
  int p = blockIdx.x * 256 + threadIdx.x;   // 4,194,304 threads
  int row = p >> 5;                         // padded row: b*1024+s
  int ch  = p & 31;                         // 8-elem chunk within H
  int s = row & (SP - 1);
  int b = row >> 10;
  float4 f0 = make_float4(0.f,0.f,0.f,0.f), f1 = f0;
  if (s < Sn){
    const float4* src = (const float4*)(stat + ((size_t)(b*Sn + s))*Hn + ch*8);
    f0 = src[0]; f1 = src[1];
  }
  bf16x8 v;
  v[0]=(bf16)f0.x; v[1]=(bf16)f0.y; v[2]=(bf16)f0.z; v[3]=(bf16)f0.w;
  v[4]=(bf16)f1.x; v[5]=(bf16)f1.y; v[6]=(bf16)f1.z; v[7]=(bf16)f1.w;
  *(bf16x8*)(Abf + (size_t)row*Hn + ch*8) = v;
}

// ---------------------------------------------------------------------------
// K0b: pack Wc (768x256 bf16, row-major) = [Wenc[:, :H]; Wtgt[:, :H]; Wptr[:, :H]]
__global__ void k0b_weights(const float* __restrict__ We, const float* __restrict__ Wt,
                            const float* __restrict__ Wp, bf16* __restrict__ Wcb){
  int t = blockIdx.x * 256 + threadIdx.x;   // 196608
  int r = t >> 8, c = t & 255;
  float val;
  if (r < 256)       val = We[r*512 + c];
  else if (r < 512)  val = Wt[(r-256)*512 + c];
  else               val = Wp[(r-512)*768 + c];
  Wcb[t] = (bf16)val;
}

// ---------------------------------------------------------------------------
// K1: GRU + bias vectors, wave-per-row dots (coalesced). grid 128 x 1024 thr.
__global__ __launch_bounds__(1024) void k1_gru(
    const float* __restrict__ dec, const float* __restrict__ lhh,
    const float* __restrict__ tgt, const float* __restrict__ se,
    const float* __restrict__ Wih, const float* __restrict__ Whh,
    const float* __restrict__ bih, const float* __restrict__ bhh,
    const float* __restrict__ We,  const float* __restrict__ Wt,
    const float* __restrict__ Wp,
    float* __restrict__ out_hh, float* __restrict__ d_enc,
    float* __restrict__ d_tgt,  float* __restrict__ c3){
  __shared__ __align__(16) float xs[256], hs[256], ts[256], ss[256], hn[256];
  __shared__ float gi[768], gh[768];
  int b = blockIdx.x, t = threadIdx.x;
  int wid = t >> 6, ln = t & 63;
  if (t < 256){
    xs[t] = dec[b*256 + t]; hs[t] = lhh[b*256 + t];
    ts[t] = tgt[b*256 + t]; ss[t] = se[b*256 + t];
  }
  __syncthreads();
  // phase 1: 1536 dots (gi: 768 rows of Wih vs x; gh: 768 rows of Whh vs h)
  #pragma unroll 2
  for (int k = 0; k < 96; k++){
    int vr = k*16 + wid;
    const float* wr; const float* xv; 
    int r;
    if (vr < 768){ r = vr;      wr = Wih + (size_t)r*256; xv = xs; }
    else         { r = vr-768;  wr = Whh + (size_t)r*256; xv = hs; }
    float d = dot4(((const float4*)wr)[ln], ((const float4*)xv)[ln]);
    d = wave_reduce(d);
    if (ln == 0){
      if (vr < 768) gi[r] = d + bih[r];
      else          gh[r] = d + bhh[r];
    }
  }
  __syncthreads();
  if (t < 256){
    float r = fast_sigmoid(gi[t] + gh[t]);
    float z = fast_sigmoid(gi[256+t] + gh[256+t]);
    float n = fast_tanh(gi[512+t] + r*gh[512+t]);
    float h = (1.f - z)*n + z*hs[t];
    hn[t] = h;
    out_hh[b*256 + t] = h;
  }
  __syncthreads();
  // phase 2: 768 dots -> d_enc, d_tgt, c3
  #pragma unroll 2
  for (int k = 0; k < 48; k++){
    int vr = k*16 + wid;
    const float* wr; const float* xv; float* dst; int r;
    if (vr < 256)      { r = vr;     wr = We + (size_t)r*512 + 256; xv = hn; dst = d_enc; }
    else if (vr < 512) { r = vr-256; wr = Wt + (size_t)r*512 + 256; xv = ts; dst = d_tgt; }
    else               { r = vr-512; wr = Wp + (size_t)r*768 + 512; xv = ss; dst = c3; }
    float d = dot4(((const float4*)wr)[ln], ((const float4*)xv)[ln]);
    d = wave_reduce(d);
    if (ln == 0) dst[b*256 + r] = d;
  }
}

// ---------------------------------------------------------------------------
// K2a: score GEMM (enc+tgt), barrier-free K-loop. A in LDS (staged once,
// XOR-swizzled), B fragments direct global->VGPR (L2-hot).
// grid (16 st, 128 b), 256 threads = 4 waves, each 32(M) x 64(N) per nc.
__global__ __launch_bounds__(256) void k2a_scores(
    const bf16* __restrict__ Abf, const bf16* __restrict__ Wcb,
    const float* __restrict__ d_enc, const float* __restrict__ d_tgt,
    const float* __restrict__ v_enc, const float* __restrict__ v_tgt,
    float* __restrict__ sc_e, float* __restrict__ sc_t){
  __shared__ __align__(16) bf16 As[64*256];    // 32 KB
  __shared__ float pS[2][64];
  int tid = threadIdx.x;
  int w = tid >> 6, l = tid & 63;
  int st = blockIdx.x, b = blockIdx.y;
  int wm = (w & 1) * 32, wn = (w >> 1) * 64;
  int lm = l & 15, q = l >> 4;

  if (tid < 64) pS[0][tid] = 0.f;
  else if (tid < 128) pS[1][tid-64] = 0.f;

  {
    const bf16* gA = Abf + ((size_t)(b*SP + st*64)) * Hn;
    int rl = w*2 + (l >> 5);
    int ch = l & 31;
    #pragma unroll
    for (int is = 0; is < 8; is++){
      int row = is*8 + rl;
      int sc_ = ch ^ (row & 7);
      __builtin_amdgcn_global_load_lds((gas1)(gA + (size_t)row*256 + sc_*8),
                                       (las3)(&As[(is*8 + w*2)*256]), 16, 0, 0);
    }
  }
  __syncthreads();

  #pragma unroll
  for (int nc = 0; nc < 4; nc++){
    f32x4 acc[2][4];
    #pragma unroll
    for (int i=0;i<2;i++)
      #pragma unroll
      for (int j=0;j<4;j++) acc[i][j] = (f32x4){0.f,0.f,0.f,0.f};
    const bf16* Bb = Wcb + ((size_t)(nc*128 + wn + lm))*256 + q*8;
    #pragma unroll
    for (int ks = 0; ks < 8; ks++){
      bf16x8 bfr[4], af[2];
      #pragma unroll
      for (int j=0;j<4;j++) bfr[j] = *(const bf16x8*)(Bb + (size_t)(j*16)*256 + ks*32);
      #pragma unroll
      for (int i=0;i<2;i++){
        int rA = wm + i*16 + lm;
        int c = (ks*4 + q) ^ (rA & 7);
        af[i] = *(const bf16x8*)(&As[rA*256 + c*8]);
      }
      #pragma unroll
      for (int i=0;i<2;i++)
        #pragma unroll
        for (int j=0;j<4;j++)
          acc[i][j] = __builtin_amdgcn_mfma_f32_16x16x32_bf16(af[i], bfr[j], acc[i][j], 0, 0, 0);
    }
    int var = nc >> 1;
    int hb = (nc & 1) * 128;
    const float* vv = var ? v_tgt : v_enc;
    const float* db = (var ? d_tgt : d_enc) + b*256;
    float vj[4], dj[4];
    #pragma unroll
    for (int j=0;j<4;j++){
      int hh = hb + wn + j*16 + lm;
      vj[j] = vv[hh]; dj[j] = db[hh];
    }
    #pragma unroll
    for (int i=0;i<2;i++){
      #pragma unroll
      for (int r=0;r<4;r++){
        float p = 0.f;
        #pragma unroll
        for (int j=0;j<4;j++) p += vj[j] * fast_tanh(acc[i][j][r] + dj[j]);
        p += __shfl_xor(p, 1);
        p += __shfl_xor(p, 2);
        p += __shfl_xor(p, 4);
        p += __shfl_xor(p, 8);
        if (lm == 0) atomicAdd(&pS[var][wm + i*16 + q*4 + r], p);
      }
    }
  }
  __syncthreads();
  if (tid < 64)       sc_e[b*SP + st*64 + tid]      = pS[0][tid];
  else if (tid < 128) sc_t[b*SP + st*64 + tid - 64] = pS[1][tid-64];
}

// ---------------------------------------------------------------------------
// K3: softmax(E,T) + context(E,T) + c2 matvec + fold c3. grid 128 x 1024 thr.
// outputs cE = c2e + c3, cT = c2t + c3.
__global__ __launch_bounds__(1024) void k3_ctx(
    const float* __restrict__ sc_e, const float* __restrict__ sc_t,
    const bf16* __restrict__ Abf, const float* __restrict__ Wp,
    const float* __restrict__ c3,
    float* __restrict__ cE, float* __restrict__ cT){
  __shared__ float attE[1024], attT[1024];
  __shared__ float redE[16], redT[16];
  __shared__ float pe[4][256], pt[4][256];
  __shared__ __align__(16) float ctxE[256], ctxT[256];
  int b = blockIdx.x, t = threadIdx.x;
  int wid = t >> 6, ln = t & 63;

  float vE = (t < Sn) ? sc_e[b*SP + t] : -1e30f;
  float vT = (t < Sn) ? sc_t[b*SP + t] : -1e30f;
  float mE = vE, mT = vT;
  #pragma unroll
  for (int o=1;o<64;o<<=1){ mE = fmaxf(mE, __shfl_xor(mE,o)); mT = fmaxf(mT, __shfl_xor(mT,o)); }
  if (ln == 0){ redE[wid] = mE; redT[wid] = mT; }
  __syncthreads();
  float ME = -1e30f, MT = -1e30f;
  #pragma unroll
  for (int i=0;i<16;i++){ ME = fmaxf(ME, redE[i]); MT = fmaxf(MT, redT[i]); }
  __syncthreads();
  float eE = (t < Sn) ? __expf(vE - ME) : 0.f;
  float eT = (t < Sn) ? __expf(vT - MT) : 0.f;
  float sE = eE, sT = eT;
  #pragma unroll
  for (int o=1;o<64;o<<=1){ sE += __shfl_xor(sE,o); sT += __shfl_xor(sT,o); }
  if (ln == 0){ redE[wid] = sE; redT[wid] = sT; }
  __syncthreads();
  float SE = 0.f, ST = 0.f;
  #pragma unroll
  for (int i=0;i<16;i++){ SE += redE[i]; ST += redT[i]; }
  attE[t] = eE / SE;
  attT[t] = eT / ST;
  __syncthreads();

  // context: thread (sh, hp) accumulates over 250 rows, both branches
  int sh = t >> 8, hp = t & 255;
  const bf16* base = Abf + ((size_t)(b*SP + sh*250))*Hn + hp;
  float aE = 0.f, aT = 0.f;
  #pragma unroll 4
  for (int i=0;i<250;i++){
    float a = (float)base[(size_t)i*Hn];
    int s = sh*250 + i;
    aE += attE[s]*a; aT += attT[s]*a;
  }
  pe[sh][hp] = aE; pt[sh][hp] = aT;
  __syncthreads();
  if (t < 256)       ctxE[t]     = pe[0][t]+pe[1][t]+pe[2][t]+pe[3][t];
  else if (t < 512){ int h=t-256; ctxT[h]  = pt[0][h]+pt[1][h]+pt[2][h]+pt[3][h]; }
  __syncthreads();
  if (t < 512){
    int h = t & 255, var = t >> 8;
    const float4* wrow = (const float4*)(Wp + (size_t)h*768 + 256);
    const float4* cv = (const float4*)(var ? ctxT : ctxE);
    float acc = 0.f;
    #pragma unroll 4
    for (int k=0;k<64;k++) acc += dot4(wrow[k], cv[k]);
    (var ? cT : cE)[b*256 + h] = acc + c3[b*256 + h];
  }
}

// ---------------------------------------------------------------------------
// K2b: ptr GEMM + fused final reduction -> out directly. Same structure as k2a.
__global__ __launch_bounds__(256) void k2b_final(
    const bf16* __restrict__ Abf, const bf16* __restrict__ Wcb,
    const float* __restrict__ cE, const float* __restrict__ cT,
    const float* __restrict__ v_ptr, float* __restrict__ out){
  __shared__ __align__(16) bf16 As[64*256];    // 32 KB
  __shared__ float pE[64], pT[64];
  int tid = threadIdx.x;
  int w = tid >> 6, l = tid & 63;
  int st = blockIdx.x, b = blockIdx.y;
  int wm = (w & 1) * 32, wn = (w >> 1) * 64;
  int lm = l & 15, q = l >> 4;

  if (tid < 64) pE[tid] = 0.f;
  else if (tid < 128) pT[tid-64] = 0.f;

  {
    const bf16* gA = Abf + ((size_t)(b*SP + st*64)) * Hn;
    int rl = w*2 + (l >> 5);
    int ch = l & 31;
    #pragma unroll
    for (int is = 0; is < 8; is++){
      int row = is*8 + rl;
      int sc_ = ch ^ (row & 7);
      __builtin_amdgcn_global_load_lds((gas1)(gA + (size_t)row*256 + sc_*8),
                                       (las3)(&As[(is*8 + w*2)*256]), 16, 0, 0);
    }
  }
  __syncthreads();

  float peA[2][4], ptA[2][4];
  #pragma unroll
  for (int i=0;i<2;i++)
    #pragma unroll
    for (int r=0;r<4;r++){ peA[i][r]=0.f; ptA[i][r]=0.f; }

  #pragma unroll
  for (int nc = 0; nc < 2; nc++){
    f32x4 acc[2][4];
    #pragma unroll
    for (int i=0;i<2;i++)
      #pragma unroll
      for (int j=0;j<4;j++) acc[i][j] = (f32x4){0.f,0.f,0.f,0.f};
    const bf16* Bb = Wcb + ((size_t)((4+nc)*128 + wn + lm))*256 + q*8;
    #pragma unroll
    for (int ks = 0; ks < 8; ks++){
      bf16x8 bfr[4], af[2];
      #pragma unroll
      for (int j=0;j<4;j++) bfr[j] = *(const bf16x8*)(Bb + (size_t)(j*16)*256 + ks*32);
      #pragma unroll
      for (int i=0;i<2;i++){
        int rA = wm + i*16 + lm;
        int c = (ks*4 + q) ^ (rA & 7);
        af[i] = *(const bf16x8*)(&As[rA*256 + c*8]);
      }
      #pragma unroll
      for (int i=0;i<2;i++)
        #pragma unroll
        for (int j=0;j<4;j++)
          acc[i][j] = __builtin_amdgcn_mfma_f32_16x16x32_bf16(af[i], bfr[j], acc[i][j], 0, 0, 0);
    }
    float vj[4], ej[4], tj[4];
    #pragma unroll
    for (int j=0;j<4;j++){
      int hh = nc*128 + wn + j*16 + lm;
      vj[j] = v_ptr[hh];
      ej[j] = cE[b*256 + hh];
      tj[j] = cT[b*256 + hh];
    }
    #pragma unroll
    for (int i=0;i<2;i++)
      #pragma unroll
      for (int r=0;r<4;r++){
        #pragma unroll
        for (int j=0;j<4;j++){
          peA[i][r] += vj[j] * fast_tanh(acc[i][j][r] + ej[j]);
          ptA[i][r] += vj[j] * fast_tanh(acc[i][j][r] + tj[j]);
        }
      }
  }
  #pragma unroll
  for (int i=0;i<2;i++){
    #pragma unroll
    for (int r=0;r<4;r++){
      float pe = peA[i][r], pt = ptA[i][r];
      pe += __shfl_xor(pe, 1); pt += __shfl_xor(pt, 1);
      pe += __shfl_xor(pe, 2); pt += __shfl_xor(pt, 2);
      pe += __shfl_xor(pe, 4); pt += __shfl_xor(pt, 4);
      pe += __shfl_xor(pe, 8); pt += __shfl_xor(pt, 8);
      if (lm == 0){
        int row = wm + i*16 + q*4 + r;
        atomicAdd(&pE[row], pe);
        atomicAdd(&pT[row], pt);
      }
    }
  }
  __syncthreads();
  if (tid < 64){
    int s = st*64 + tid;
    if (s < Sn) out[b*Sn + s] = 5.0f*pE[tid] + pT[tid];
  }
}

// ---------------------------------------------------------------------------
extern "C" void kernel_launch(void* const* d_in, const int* in_sizes, int n_in,
                              void* d_out, int out_size, void* d_ws, size_t ws_size,
                              hipStream_t stream){
  const float* stat = (const float*)d_in[0];
  const float* se   = (const float*)d_in[1];
  const float* dec  = (const float*)d_in[2];
  const float* tgt  = (const float*)d_in[3];
  const float* lhh  = (const float*)d_in[4];
  const float* Wih  = (const float*)d_in[5];
  const float* Whh  = (const float*)d_in[6];
  const float* bih  = (const float*)d_in[7];
  const float* bhh  = (const float*)d_in[8];
  const float* vEnc = (const float*)d_in[9];
  const float* WEnc = (const float*)d_in[10];
  const float* vTgt = (const float*)d_in[11];
  const float* WTgt = (const float*)d_in[12];
  const float* vPtr = (const float*)d_in[13];
  const float* WPtr = (const float*)d_in[14];
  float* out = (float*)d_out;

  char* wsp = (char*)d_ws;
  bf16*  Abf  = (bf16*)(wsp);                  // 67,108,864
  bf16*  Wcb  = (bf16*)(wsp + 67108864);       // 393,216
  float* scE  = (float*)(wsp + 67502080);      // 524,288
  float* scT  = (float*)(wsp + 68026368);      // 524,288
  float* dEnc = (float*)(wsp + 68550656);      // 131,072
  float* dTgt = (float*)(wsp + 68681728);      // 131,072
  float* c3   = (float*)(wsp + 68812800);      // 131,072
  float* cE   = (float*)(wsp + 68943872);      // 131,072
  float* cT   = (float*)(wsp + 69074944);      // 131,072 -> end 69,206,016

  hipLaunchKernelGGL(k0a_convert, dim3(16384), dim3(256), 0, stream, stat, Abf);
  hipLaunchKernelGGL(k0b_weights, dim3(768), dim3(256), 0, stream, WEnc, WTgt, WPtr, Wcb);
  hipLaunchKernelGGL(k1_gru, dim3(128), dim3(1024), 0, stream,
                     dec, lhh, tgt, se, Wih, Whh, bih, bhh, WEnc, WTgt, WPtr,
                     out + Bn*Sn, dEnc, dTgt, c3);
  hipLaunchKernelGGL(k2a_scores, dim3(16, 128), dim3(256), 0, stream,
                     Abf, Wcb, dEnc, dTgt, vEnc, vTgt, scE, scT);
  hipLaunchKernelGGL(k3_ctx, dim3(128), dim3(1024), 0, stream,
                     scE, scT, Abf, WPtr, c3, cE, cT);
  hipLaunchKernelGGL(k2b_final, dim3(16, 128), dim3(256), 0, stream,
                     Abf, Wcb, cE, cT, vPtr, out);
}

// Round 4
// 518.924 us; speedup vs baseline: 1.1354x; 1.1354x over previous
//
#include <hip/hip_runtime.h>
#include <hip/hip_bf16.h>
#include <stdint.h>
#include <stddef.h>

// Problem dims
#define Bn 128
#define Sn 1000
#define SP 1024   // padded S
#define Hn 256

typedef __bf16 bf16;
typedef __bf16 bf16x8 __attribute__((ext_vector_type(8)));
typedef __bf16 bf16x4 __attribute__((ext_vector_type(4)));
typedef float  f32x4  __attribute__((ext_vector_type(4)));

typedef __attribute__((address_space(1))) const unsigned int* gas1;
typedef __attribute__((address_space(3))) unsigned int* las3;

__device__ __forceinline__ float fast_tanh(float x){
  return 1.0f - 2.0f / (__expf(2.0f * x) + 1.0f);
}
__device__ __forceinline__ float fast_sigmoid(float x){
  return 1.0f / (1.0f + __expf(-x));
}
__device__ __forceinline__ float dot4(float4 a, float4 b){
  return a.x*b.x + a.y*b.y + a.z*b.z + a.w*b.w;
}
__device__ __forceinline__ float wave_reduce(float v){
  #pragma unroll
  for (int o=1;o<64;o<<=1) v += __shfl_xor(v, o);
  return v;
}

// ---------------------------------------------------------------------------
// K0a: static fp32 -> bf16, padded to (B,1024,H); pad rows zero.
__global__ void k0a_convert(const float* __restrict__ stat, bf16* __restrict__ Abf){
  int p = blockIdx.x * 256 + threadIdx.x;
  int row = p >> 5;
  int ch  = p & 31;
  int s = row & (SP - 1);
  int b = row >> 10;
  float4 f0 = make_float4(0.f,0.f,0.f,0.f), f1 = f0;
  if (s < Sn){
    const float4* src = (const float4*)(stat + ((size_t)(b*Sn + s))*Hn + ch*8);
    f0 = src[0]; f1 = src[1];
  }
  bf16x8 v;
  v[0]=(bf16)f0.x; v[1]=(bf16)f0.y; v[2]=(bf16)f0.z; v[3]=(bf16)f0.w;
  v[4]=(bf16)f1.x; v[5]=(bf16)f1.y; v[6]=(bf16)f1.z; v[7]=(bf16)f1.w;
  *(bf16x8*)(Abf + (size_t)row*Hn + ch*8) = v;
}

// ---------------------------------------------------------------------------
// K0b: pack Wc (768x256 bf16) = [Wenc[:, :H]; Wtgt[:, :H]; Wptr[:, :H]]
__global__ void k0b_weights(const float* __restrict__ We, const float* __restrict__ Wt,
                            const float* __restrict__ Wp, bf16* __restrict__ Wcb){
  int t = blockIdx.x * 256 + threadIdx.x;
  int r = t >> 8, c = t & 255;
  float val;
  if (r < 256)       val = We[r*512 + c];
  else if (r < 512)  val = Wt[(r-256)*512 + c];
  else               val = Wp[(r-512)*768 + c];
  Wcb[t] = (bf16)val;
}

// ---------------------------------------------------------------------------
// K1: GRU + bias vectors, wave-per-row dots. grid 128 x 1024 thr.
__global__ __launch_bounds__(1024) void k1_gru(
    const float* __restrict__ dec, const float* __restrict__ lhh,
    const float* __restrict__ tgt, const float* __restrict__ se,
    const float* __restrict__ Wih, const float* __restrict__ Whh,
    const float* __restrict__ bih, const float* __restrict__ bhh,
    const float* __restrict__ We,  const float* __restrict__ Wt,
    const float* __restrict__ Wp,
    float* __restrict__ out_hh, float* __restrict__ d_enc,
    float* __restrict__ d_tgt,  float* __restrict__ c3){
  __shared__ __align__(16) float xs[256], hs[256], ts[256], ss[256], hn[256];
  __shared__ float gi[768], gh[768];
  int b = blockIdx.x, t = threadIdx.x;
  int wid = t >> 6, ln = t & 63;
  if (t < 256){
    xs[t] = dec[b*256 + t]; hs[t] = lhh[b*256 + t];
    ts[t] = tgt[b*256 + t]; ss[t] = se[b*256 + t];
  }
  __syncthreads();
  #pragma unroll 2
  for (int k = 0; k < 96; k++){
    int vr = k*16 + wid;
    const float* wr; const float* xv;
    int r;
    if (vr < 768){ r = vr;      wr = Wih + (size_t)r*256; xv = xs; }
    else         { r = vr-768;  wr = Whh + (size_t)r*256; xv = hs; }
    float d = dot4(((const float4*)wr)[ln], ((const float4*)xv)[ln]);
    d = wave_reduce(d);
    if (ln == 0){
      if (vr < 768) gi[r] = d + bih[r];
      else          gh[r] = d + bhh[r];
    }
  }
  __syncthreads();
  if (t < 256){
    float r = fast_sigmoid(gi[t] + gh[t]);
    float z = fast_sigmoid(gi[256+t] + gh[256+t]);
    float n = fast_tanh(gi[512+t] + r*gh[512+t]);
    float h = (1.f - z)*n + z*hs[t];
    hn[t] = h;
    out_hh[b*256 + t] = h;
  }
  __syncthreads();
  #pragma unroll 2
  for (int k = 0; k < 48; k++){
    int vr = k*16 + wid;
    const float* wr; const float* xv; float* dst; int r;
    if (vr < 256)      { r = vr;     wr = We + (size_t)r*512 + 256; xv = hn; dst = d_enc; }
    else if (vr < 512) { r = vr-256; wr = Wt + (size_t)r*512 + 256; xv = ts; dst = d_tgt; }
    else               { r = vr-512; wr = Wp + (size_t)r*768 + 512; xv = ss; dst = c3; }
    float d = dot4(((const float4*)wr)[ln], ((const float4*)xv)[ln]);
    d = wave_reduce(d);
    if (ln == 0) dst[b*256 + r] = d;
  }
}

// ---------------------------------------------------------------------------
// K2: fused GEMM, all 6 N-chunks. A staged once (32 KB, XOR-swizzled);
// B staged per (pair, kt) as 2x16 KB. 512 thr = 8 waves: wave = 16(M) x 64(N).
// Scores -> LDS reduce -> sc_e/sc_t. Ptr chunks -> Aptr in C-reg layout:
//   slot = buf*4 + r (bf16x4 over j), addr = block*16384 + (slot*512 + tid)*4.
__global__ __launch_bounds__(512) void k2_gemm(
    const bf16* __restrict__ Abf, const bf16* __restrict__ Wcb,
    const float* __restrict__ d_enc, const float* __restrict__ d_tgt,
    const float* __restrict__ v_enc, const float* __restrict__ v_tgt,
    float* __restrict__ sc_e, float* __restrict__ sc_t, bf16* __restrict__ Aptr){
  __shared__ __align__(16) bf16 As[64*256];      // 32 KB
  __shared__ __align__(16) bf16 Bs[2][128*64];   // 32 KB
  __shared__ float pS[2][64];
  int tid = threadIdx.x, w = tid>>6, l = tid&63;
  int st = blockIdx.x, b = blockIdx.y;
  int wm = (w&3)*16, wn = (w>>2)*64;
  int lm = l&15, q = l>>4;
  if (tid < 64){ pS[0][tid]=0.f; pS[1][tid]=0.f; }

  // stage A (64 rows x 256 K), swizzled: chunk c of row r at c^(r&7)
  {
    const bf16* gA = Abf + ((size_t)(b*SP + st*64))*Hn;
    int rl = w*2 + (l>>5);       // 0..15
    int ch = l & 31;
    #pragma unroll
    for (int is=0; is<4; is++){
      int row = is*16 + rl;
      int sc_ = ch ^ (row & 7);
      __builtin_amdgcn_global_load_lds((gas1)(gA + (size_t)row*256 + sc_*8),
                                       (las3)(&As[(is*16 + w*2)*256]), 16, 0, 0);
    }
  }

  for (int p=0; p<3; p++){
    f32x4 acc[2][4];
    #pragma unroll
    for (int u=0;u<2;u++)
      #pragma unroll
      for (int j=0;j<4;j++) acc[u][j] = (f32x4){0.f,0.f,0.f,0.f};

    for (int kt=0; kt<4; kt++){
      __syncthreads();
      #pragma unroll
      for (int buf=0; buf<2; buf++){
        int nc = p*2 + buf;
        #pragma unroll
        for (int is=0; is<2; is++){
          int row = w*16 + is*8 + (l>>3);
          int sc_ = (l&7) ^ (row & 7);
          __builtin_amdgcn_global_load_lds(
              (gas1)(Wcb + ((size_t)(nc*128 + row))*256 + kt*64 + sc_*8),
              (las3)(&Bs[buf][(w*16 + is*8)*64]), 16, 0, 0);
        }
      }
      __syncthreads();
      #pragma unroll
      for (int kk=0; kk<2; kk++){
        bf16x8 af;
        {
          int rA = wm + lm;
          int c = (kt*8 + kk*4 + q) ^ (rA & 7);
          af = *(const bf16x8*)(&As[rA*256 + c*8]);
        }
        #pragma unroll
        for (int buf=0; buf<2; buf++){
          #pragma unroll
          for (int j=0;j<4;j++){
            int rB = wn + j*16 + lm;
            int cB = (kk*4 + q) ^ (rB & 7);
            bf16x8 bf_ = *(const bf16x8*)(&Bs[buf][rB*64 + cB*8]);
            acc[buf][j] = __builtin_amdgcn_mfma_f32_16x16x32_bf16(af, bf_, acc[buf][j], 0,0,0);
          }
        }
      }
    }

    if (p < 2){
      const float* vv = p ? v_tgt : v_enc;
      const float* db = (p ? d_tgt : d_enc) + b*256;
      #pragma unroll
      for (int buf=0; buf<2; buf++){
        float vj[4], dj[4];
        #pragma unroll
        for (int j=0;j<4;j++){
          int hh = buf*128 + wn + j*16 + lm;
          vj[j] = vv[hh]; dj[j] = db[hh];
        }
        #pragma unroll
        for (int r=0;r<4;r++){
          float pp = 0.f;
          #pragma unroll
          for (int j=0;j<4;j++) pp += vj[j]*fast_tanh(acc[buf][j][r] + dj[j]);
          pp += __shfl_xor(pp,1); pp += __shfl_xor(pp,2);
          pp += __shfl_xor(pp,4); pp += __shfl_xor(pp,8);
          if (lm == 0) atomicAdd(&pS[p][wm + q*4 + r], pp);
        }
      }
    } else {
      bf16* dst = Aptr + ((size_t)(b*16 + st))*16384;
      #pragma unroll
      for (int buf=0; buf<2; buf++){
        #pragma unroll
        for (int r=0;r<4;r++){
          bf16x4 v4;
          #pragma unroll
          for (int j=0;j<4;j++) v4[j] = (bf16)acc[buf][j][r];
          int slot = buf*4 + r;
          *(bf16x4*)(dst + ((size_t)(slot*512 + tid))*4) = v4;
        }
      }
    }
  }
  __syncthreads();
  if (tid < 64)        sc_e[b*SP + st*64 + tid]        = pS[0][tid];
  else if (tid < 128)  sc_t[b*SP + st*64 + (tid-64)]   = pS[1][tid-64];
}

// ---------------------------------------------------------------------------
// K3: softmax stats (full S, both branches) + context partial over 250 rows.
// grid (128 b, 4 sq) x 256. ctxP bf16 [var][sq][b][h].
__global__ __launch_bounds__(256) void k3_ctx(
    const float* __restrict__ sc_e, const float* __restrict__ sc_t,
    const bf16* __restrict__ Abf, bf16* __restrict__ ctxP){
  __shared__ float attE[256], attT[256];
  __shared__ float red[16];
  int b = blockIdx.x, sq = blockIdx.y, t = threadIdx.x;
  int wid = t>>6, ln = t&63;

  float mE=-1e30f, mT=-1e30f;
  #pragma unroll
  for (int i=0;i<4;i++){
    int s = t + i*256;
    if (s < Sn){
      mE = fmaxf(mE, sc_e[b*SP+s]);
      mT = fmaxf(mT, sc_t[b*SP+s]);
    }
  }
  #pragma unroll
  for (int o=1;o<64;o<<=1){ mE=fmaxf(mE,__shfl_xor(mE,o)); mT=fmaxf(mT,__shfl_xor(mT,o)); }
  if (ln==0){ red[wid*2]=mE; red[wid*2+1]=mT; }
  __syncthreads();
  float ME = fmaxf(fmaxf(red[0],red[2]), fmaxf(red[4],red[6]));
  float MT = fmaxf(fmaxf(red[1],red[3]), fmaxf(red[5],red[7]));
  float sE=0.f, sT=0.f;
  #pragma unroll
  for (int i=0;i<4;i++){
    int s = t + i*256;
    if (s < Sn){
      sE += __expf(sc_e[b*SP+s] - ME);
      sT += __expf(sc_t[b*SP+s] - MT);
    }
  }
  #pragma unroll
  for (int o=1;o<64;o<<=1){ sE+=__shfl_xor(sE,o); sT+=__shfl_xor(sT,o); }
  __syncthreads();
  if (ln==0){ red[wid*2]=sE; red[wid*2+1]=sT; }
  __syncthreads();
  float invE = 1.f/(red[0]+red[2]+red[4]+red[6]);
  float invT = 1.f/(red[1]+red[3]+red[5]+red[7]);

  int r0 = sq*250;
  if (t < 250){
    int s = r0 + t;
    attE[t] = __expf(sc_e[b*SP+s] - ME)*invE;
    attT[t] = __expf(sc_t[b*SP+s] - MT)*invT;
  }
  __syncthreads();

  const bf16* base = Abf + ((size_t)(b*SP + r0))*Hn + t;
  float aE=0.f, aT=0.f;
  #pragma unroll 2
  for (int i=0;i<250;i++){
    float a = (float)base[(size_t)i*Hn];
    aE += attE[i]*a;
    aT += attT[i]*a;
  }
  ctxP[(((size_t)sq)*128 + b)*256 + t]       = (bf16)aE;
  ctxP[(((size_t)(4 + sq))*128 + b)*256 + t] = (bf16)aT;
}

// ---------------------------------------------------------------------------
// K3c: ctx = sum partials; c2 = Wptr[:,H:2H]@ctx; cE/cT = c2 + c3. grid 128 x 1024.
__global__ __launch_bounds__(1024) void k3c_c2(
    const bf16* __restrict__ ctxP, const float* __restrict__ Wp,
    const float* __restrict__ c3,
    float* __restrict__ cE, float* __restrict__ cT){
  __shared__ __align__(16) float ctx[2][256];
  int b = blockIdx.x, t = threadIdx.x;
  int wid = t>>6, ln = t&63;
  if (t < 512){
    int var = t>>8, h = t&255;
    float s = 0.f;
    #pragma unroll
    for (int sqq=0; sqq<4; sqq++)
      s += (float)ctxP[(((size_t)(var*4 + sqq))*128 + b)*256 + h];
    ctx[var][h] = s;
  }
  __syncthreads();
  #pragma unroll 2
  for (int k=0;k<32;k++){
    int vr = k*16 + wid;
    int var = vr>>8, h = vr&255;
    float d = dot4(((const float4*)(Wp + (size_t)h*768 + 256))[ln],
                   ((const float4*)ctx[var])[ln]);
    d = wave_reduce(d);
    if (ln==0) (var ? cT : cE)[b*256 + h] = d + c3[b*256 + h];
  }
}

// ---------------------------------------------------------------------------
// K4: final reduction from Aptr (C-reg layout, coalesced). grid (16,128) x 512.
__global__ __launch_bounds__(512) void k4_final(
    const bf16* __restrict__ Aptr, const float* __restrict__ cE,
    const float* __restrict__ cT, const float* __restrict__ vp,
    float* __restrict__ out){
  __shared__ float pE[64], pT[64];
  int tid=threadIdx.x, w=tid>>6, l=tid&63;
  int st=blockIdx.x, b=blockIdx.y;
  int wm=(w&3)*16, wn=(w>>2)*64, lm=l&15, q=l>>4;
  if (tid < 64){ pE[tid]=0.f; pT[tid]=0.f; }
  __syncthreads();
  const bf16* src = Aptr + ((size_t)(b*16 + st))*16384;
  float vj[8], ej[8], tj[8];
  #pragma unroll
  for (int u=0;u<8;u++){
    int hh = (u>>2)*128 + wn + (u&3)*16 + lm;
    vj[u]=vp[hh]; ej[u]=cE[b*256+hh]; tj[u]=cT[b*256+hh];
  }
  float peR[4]={0.f,0.f,0.f,0.f}, ptR[4]={0.f,0.f,0.f,0.f};
  #pragma unroll
  for (int buf=0;buf<2;buf++){
    #pragma unroll
    for (int r=0;r<4;r++){
      bf16x4 v4 = *(const bf16x4*)(src + ((size_t)((buf*4+r)*512 + tid))*4);
      #pragma unroll
      for (int j=0;j<4;j++){
        float a = (float)v4[j];
        int u = buf*4 + j;
        peR[r] += vj[u]*fast_tanh(a + ej[u]);
        ptR[r] += vj[u]*fast_tanh(a + tj[u]);
      }
    }
  }
  #pragma unroll
  for (int r=0;r<4;r++){
    float pe = peR[r], pt = ptR[r];
    pe += __shfl_xor(pe,1); pt += __shfl_xor(pt,1);
    pe += __shfl_xor(pe,2); pt += __shfl_xor(pt,2);
    pe += __shfl_xor(pe,4); pt += __shfl_xor(pt,4);
    pe += __shfl_xor(pe,8); pt += __shfl_xor(pt,8);
    if (lm==0){
      atomicAdd(&pE[wm + q*4 + r], pe);
      atomicAdd(&pT[wm + q*4 + r], pt);
    }
  }
  __syncthreads();
  if (tid < 64){
    int s = st*64 + tid;
    if (s < Sn) out[b*Sn + s] = 5.0f*pE[tid] + pT[tid];
  }
}

// ---------------------------------------------------------------------------
extern "C" void kernel_launch(void* const* d_in, const int* in_sizes, int n_in,
                              void* d_out, int out_size, void* d_ws, size_t ws_size,
                              hipStream_t stream){
  const float* stat = (const float*)d_in[0];
  const float* se   = (const float*)d_in[1];
  const float* dec  = (const float*)d_in[2];
  const float* tgt  = (const float*)d_in[3];
  const float* lhh  = (const float*)d_in[4];
  const float* Wih  = (const float*)d_in[5];
  const float* Whh  = (const float*)d_in[6];
  const float* bih  = (const float*)d_in[7];
  const float* bhh  = (const float*)d_in[8];
  const float* vEnc = (const float*)d_in[9];
  const float* WEnc = (const float*)d_in[10];
  const float* vTgt = (const float*)d_in[11];
  const float* WTgt = (const float*)d_in[12];
  const float* vPtr = (const float*)d_in[13];
  const float* WPtr = (const float*)d_in[14];
  float* out = (float*)d_out;

  char* wsp = (char*)d_ws;
  // layout (bytes); ctxP (bf16, 524288) aliases Wcb+dEnc (both dead after k2):
  bf16*  Abf  = (bf16*)(wsp);                    // 67,108,864
  bf16*  Aptr = (bf16*)(wsp + 67108864);         // 67,108,864
  bf16*  Wcb  = (bf16*)(wsp + 134217728);        // 393,216
  float* dEnc = (float*)(wsp + 134610944);       // 131,072
  bf16*  ctxP = (bf16*)(wsp + 134217728);        // 524,288 (alias, used in k3/k3c)
  float* dTgt = (float*)(wsp + 134742016);       // 131,072
  float* scE  = (float*)(wsp + 134873088);       // 524,288
  float* scT  = (float*)(wsp + 135397376);       // 524,288
  float* c3   = (float*)(wsp + 135921664);       // 131,072
  float* cE   = (float*)(wsp + 136052736);       // 131,072
  float* cT   = (float*)(wsp + 136183808);       // 131,072 -> end 136,314,880

  hipLaunchKernelGGL(k0a_convert, dim3(16384), dim3(256), 0, stream, stat, Abf);
  hipLaunchKernelGGL(k0b_weights, dim3(768), dim3(256), 0, stream, WEnc, WTgt, WPtr, Wcb);
  hipLaunchKernelGGL(k1_gru, dim3(128), dim3(1024), 0, stream,
                     dec, lhh, tgt, se, Wih, Whh, bih, bhh, WEnc, WTgt, WPtr,
                     out + Bn*Sn, dEnc, dTgt, c3);
  hipLaunchKernelGGL(k2_gemm, dim3(16, 128), dim3(512), 0, stream,
                     Abf, Wcb, dEnc, dTgt, vEnc, vTgt, scE, scT, Aptr);
  hipLaunchKernelGGL(k3_ctx, dim3(128, 4), dim3(256), 0, stream,
                     scE, scT, Abf, ctxP);
  hipLaunchKernelGGL(k3c_c2, dim3(128), dim3(1024), 0, stream,
                     ctxP, WPtr, c3, cE, cT);
  hipLaunchKernelGGL(k4_final, dim3(16, 128), dim3(512), 0, stream,
                     Aptr, cE, cT, vPtr, out);
}

// Round 5
// 458.398 us; speedup vs baseline: 1.2853x; 1.1320x over previous
//
#include <hip/hip_runtime.h>
#include <hip/hip_bf16.h>
#include <stdint.h>
#include <stddef.h>

#define Bn 128
#define Sn 1000
#define SP 1024
#define Hn 256

typedef __bf16 bf16;
typedef __bf16 bf16x8 __attribute__((ext_vector_type(8)));
typedef __bf16 bf16x4 __attribute__((ext_vector_type(4)));
typedef float  f32x4  __attribute__((ext_vector_type(4)));

typedef __attribute__((address_space(1))) const unsigned int* gas1;
typedef __attribute__((address_space(3))) unsigned int* las3;

__device__ __forceinline__ float fast_tanh(float x){
  return 1.0f - 2.0f / (__expf(2.0f * x) + 1.0f);
}
__device__ __forceinline__ float fast_sigmoid(float x){
  return 1.0f / (1.0f + __expf(-x));
}

// ---------------------------------------------------------------------------
// K0w: pack Wc (768x256 bf16) and transpose dec/lhh/tgt/se to [k][b].
// grid 1280 x 256.
__global__ void k0w(const float* __restrict__ We, const float* __restrict__ Wt,
                    const float* __restrict__ Wp, bf16* __restrict__ Wcb,
                    const float* __restrict__ dec, const float* __restrict__ lhh,
                    const float* __restrict__ tgt, const float* __restrict__ se,
                    float* __restrict__ xT, float* __restrict__ hT,
                    float* __restrict__ tT, float* __restrict__ sT){
  int blk = blockIdx.x, t = threadIdx.x;
  if (blk < 768){
    int tt = blk*256 + t;
    int r = tt >> 8, c = tt & 255;
    float val;
    if (r < 256)       val = We[r*512 + c];
    else if (r < 512)  val = Wt[(r-256)*512 + c];
    else               val = Wp[(r-512)*768 + c];
    Wcb[tt] = (bf16)val;
  } else {
    int idx = blk - 768;           // 0..511
    int a = idx >> 7, bb = idx & 127;
    const float* src = (a==0) ? dec : (a==1) ? lhh : (a==2) ? tgt : se;
    float* dst       = (a==0) ? xT  : (a==1) ? hT  : (a==2) ? tT  : sT;
    dst[t*128 + bb] = src[bb*256 + t];
  }
}

// ---------------------------------------------------------------------------
// K1a: fused GRU. grid 64 x 512: 4 groups of 128 b-lanes, group handles one h.
// All 6 gate dots in one k-loop (W wave-uniform s_loads, xT/hT coalesced).
__global__ __launch_bounds__(512) void k1a_gru(
    const float* __restrict__ xT, const float* __restrict__ hT,
    const float* __restrict__ Wih, const float* __restrict__ Whh,
    const float* __restrict__ bih, const float* __restrict__ bhh,
    float* __restrict__ out_hh, float* __restrict__ hnT){
  int t = threadIdx.x;
  int g = t >> 7, b = t & 127;
  int h = blockIdx.x*4 + g;
  const float4* wir = (const float4*)(Wih + (size_t)h*256);
  const float4* wiz = (const float4*)(Wih + (size_t)(256+h)*256);
  const float4* wig = (const float4*)(Wih + (size_t)(512+h)*256);
  const float4* whr = (const float4*)(Whh + (size_t)h*256);
  const float4* whz = (const float4*)(Whh + (size_t)(256+h)*256);
  const float4* whg = (const float4*)(Whh + (size_t)(512+h)*256);
  float air=0.f, aiz=0.f, aig=0.f, ahr=0.f, ahz=0.f, ahg=0.f;
  #pragma unroll 2
  for (int kq=0; kq<64; kq++){
    float4 vir = wir[kq], viz = wiz[kq], vig = wig[kq];
    float4 vhr = whr[kq], vhz = whz[kq], vhg = whg[kq];
    #pragma unroll
    for (int e=0;e<4;e++){
      int k = kq*4 + e;
      float xv = xT[k*128 + b];
      float hv = hT[k*128 + b];
      float wi_r = (&vir.x)[e], wi_z = (&viz.x)[e], wi_g = (&vig.x)[e];
      float wh_r = (&vhr.x)[e], wh_z = (&vhz.x)[e], wh_g = (&vhg.x)[e];
      air += wi_r*xv; aiz += wi_z*xv; aig += wi_g*xv;
      ahr += wh_r*hv; ahz += wh_z*hv; ahg += wh_g*hv;
    }
  }
  air += bih[h];      ahr += bhh[h];
  aiz += bih[256+h];  ahz += bhh[256+h];
  aig += bih[512+h];  ahg += bhh[512+h];
  float r = fast_sigmoid(air + ahr);
  float z = fast_sigmoid(aiz + ahz);
  float n = fast_tanh(aig + r*ahg);
  float hprev = hT[h*128 + b];
  float hnew = (1.f - z)*n + z*hprev;
  out_hh[b*256 + h] = hnew;
  hnT[h*128 + b] = hnew;
}

// ---------------------------------------------------------------------------
// K1c: d_enc/d_tgt/c3 dots. grid 192 x 512: group per row vr=blk*4+g (0..767).
__global__ __launch_bounds__(512) void k1c_dots(
    const float* __restrict__ hnT, const float* __restrict__ tT,
    const float* __restrict__ sT,
    const float* __restrict__ We, const float* __restrict__ Wt,
    const float* __restrict__ Wp,
    float* __restrict__ dEnc, float* __restrict__ dTgt, float* __restrict__ c3){
  int t = threadIdx.x;
  int g = t >> 7, b = t & 127;
  int vr = blockIdx.x*4 + g;
  int var = vr >> 8, h = vr & 255;
  const float* wrow; const float* X; float* dst;
  if (var == 0)      { wrow = We + (size_t)h*512 + 256; X = hnT; dst = dEnc; }
  else if (var == 1) { wrow = Wt + (size_t)h*512 + 256; X = tT;  dst = dTgt; }
  else               { wrow = Wp + (size_t)h*768 + 512; X = sT;  dst = c3; }
  const float4* w4 = (const float4*)wrow;
  float acc = 0.f;
  #pragma unroll 2
  for (int kq=0; kq<64; kq++){
    float4 wv = w4[kq];
    #pragma unroll
    for (int e=0;e<4;e++)
      acc += (&wv.x)[e] * X[(kq*4+e)*128 + b];
  }
  dst[b*256 + h] = acc;
}

// ---------------------------------------------------------------------------
// K2: fused GEMM. A staged fp32->bf16->LDS once per block (swizzled);
// 3 phases of nc-pairs; B (32 KB per (p,kt)) via global_load_lds.
// 256 thr = 4 waves, each 64(M) x 64(N): 4x4 frags -> 16 MFMA per 8 ds_reads.
__global__ __launch_bounds__(256) void k2_gemm(
    const float* __restrict__ stat, const bf16* __restrict__ Wcb,
    const float* __restrict__ dEnc, const float* __restrict__ dTgt,
    const float* __restrict__ vEnc, const float* __restrict__ vTgt,
    float* __restrict__ scE, float* __restrict__ scT, bf16* __restrict__ Aptr){
  __shared__ __align__(16) bf16 As[64*256];   // 32 KB
  __shared__ __align__(16) bf16 Bs[256*64];   // 32 KB
  __shared__ float pS[2][64];
  int tid = threadIdx.x, w = tid>>6, l = tid&63;
  int st = blockIdx.x, b = blockIdx.y;
  int lm = l&15, q = l>>4;
  if (tid < 128) pS[tid>>6][tid&63] = 0.f;

  // A stage: 16 coalesced issues; float4 -> bf16x4 ds_write_b64 (swizzled).
  {
    #pragma unroll
    for (int is=0; is<16; is++){
      int fidx = is*256 + tid;       // float4 index in 64x64
      int row = fidx >> 6;
      int col4 = fidx & 63;
      int s = st*64 + row;
      float4 f = make_float4(0.f,0.f,0.f,0.f);
      if (s < Sn)
        f = ((const float4*)(stat + ((size_t)(b*Sn + s))*Hn))[col4];
      bf16x4 v;
      v[0]=(bf16)f.x; v[1]=(bf16)f.y; v[2]=(bf16)f.z; v[3]=(bf16)f.w;
      int c8 = col4 >> 1, half = col4 & 1;
      *(bf16x4*)(&As[row*256 + ((c8 ^ (row&7))<<3) + half*4]) = v;
    }
  }

  for (int p=0; p<3; p++){
    f32x4 acc[4][4];
    #pragma unroll
    for (int i=0;i<4;i++)
      #pragma unroll
      for (int j=0;j<4;j++) acc[i][j] = (f32x4){0.f,0.f,0.f,0.f};

    for (int kt=0; kt<4; kt++){
      __syncthreads();
      #pragma unroll
      for (int is=0; is<8; is++){
        int row = w*64 + is*8 + (l>>3);
        int sc_ = (l&7) ^ (row & 7);
        __builtin_amdgcn_global_load_lds(
            (gas1)(Wcb + ((size_t)(p*256 + row))*256 + kt*64 + sc_*8),
            (las3)(&Bs[(w*64 + is*8)*64]), 16, 0, 0);
      }
      __syncthreads();
      #pragma unroll
      for (int kk=0; kk<2; kk++){
        bf16x8 af[4], bfr[4];
        #pragma unroll
        for (int i=0;i<4;i++){
          int rA = i*16 + lm;
          int c = (kt*8 + kk*4 + q) ^ (rA & 7);
          af[i] = *(const bf16x8*)(&As[rA*256 + c*8]);
        }
        #pragma unroll
        for (int j=0;j<4;j++){
          int rB = w*64 + j*16 + lm;
          int cB = (kk*4 + q) ^ (rB & 7);
          bfr[j] = *(const bf16x8*)(&Bs[rB*64 + cB*8]);
        }
        #pragma unroll
        for (int i=0;i<4;i++)
          #pragma unroll
          for (int j=0;j<4;j++)
            acc[i][j] = __builtin_amdgcn_mfma_f32_16x16x32_bf16(af[i], bfr[j], acc[i][j], 0,0,0);
      }
    }

    if (p < 2){
      const float* vv = p ? vTgt : vEnc;
      const float* db = (p ? dTgt : dEnc) + b*256;
      float vj[4], dj[4];
      #pragma unroll
      for (int j=0;j<4;j++){
        int hh = w*64 + j*16 + lm;
        vj[j] = vv[hh]; dj[j] = db[hh];
      }
      #pragma unroll
      for (int i=0;i<4;i++){
        #pragma unroll
        for (int r=0;r<4;r++){
          float pp = 0.f;
          #pragma unroll
          for (int j=0;j<4;j++) pp += vj[j]*fast_tanh(acc[i][j][r] + dj[j]);
          pp += __shfl_xor(pp,1); pp += __shfl_xor(pp,2);
          pp += __shfl_xor(pp,4); pp += __shfl_xor(pp,8);
          if (lm == 0) atomicAdd(&pS[p][i*16 + q*4 + r], pp);
        }
      }
    } else {
      bf16* dst = Aptr + ((size_t)(b*16 + st))*16384;
      #pragma unroll
      for (int i=0;i<4;i++){
        #pragma unroll
        for (int r=0;r<4;r++){
          bf16x4 v4;
          #pragma unroll
          for (int j=0;j<4;j++) v4[j] = (bf16)acc[i][j][r];
          int slot = i*4 + r;
          *(bf16x4*)(dst + ((size_t)((slot*4 + w)*64 + l))*4) = v4;
        }
      }
    }
  }
  __syncthreads();
  if (tid < 64)        scE[b*SP + st*64 + tid]      = pS[0][tid];
  else if (tid < 128)  scT[b*SP + st*64 + tid-64]   = pS[1][tid-64];
}

// ---------------------------------------------------------------------------
// K3: softmax (full S, both branches) + context over 500 rows (4 subgroups).
// grid (128 b, 2 sq) x 1024. ctxP fp32 [var*2+sq][h][b].
__global__ __launch_bounds__(1024) void k3_ctx(
    const float* __restrict__ scE, const float* __restrict__ scT,
    const float* __restrict__ stat, float* __restrict__ ctxP){
  __shared__ float attE[500], attT[500];
  __shared__ float redE[16], redT[16];
  __shared__ float pe[4][256], pt[4][256];
  int b = blockIdx.x, sq = blockIdx.y, t = threadIdx.x;
  int wid = t>>6, ln = t&63;

  float vE = (t < Sn) ? scE[b*SP + t] : -1e30f;
  float vT = (t < Sn) ? scT[b*SP + t] : -1e30f;
  float mE = vE, mT = vT;
  #pragma unroll
  for (int o=1;o<64;o<<=1){ mE=fmaxf(mE,__shfl_xor(mE,o)); mT=fmaxf(mT,__shfl_xor(mT,o)); }
  if (ln==0){ redE[wid]=mE; redT[wid]=mT; }
  __syncthreads();
  float ME=-1e30f, MT=-1e30f;
  #pragma unroll
  for (int i=0;i<16;i++){ ME=fmaxf(ME,redE[i]); MT=fmaxf(MT,redT[i]); }
  __syncthreads();
  float eE = (t < Sn) ? __expf(vE-ME) : 0.f;
  float eT = (t < Sn) ? __expf(vT-MT) : 0.f;
  float sE=eE, sT=eT;
  #pragma unroll
  for (int o=1;o<64;o<<=1){ sE+=__shfl_xor(sE,o); sT+=__shfl_xor(sT,o); }
  if (ln==0){ redE[wid]=sE; redT[wid]=sT; }
  __syncthreads();
  float SE=0.f, ST=0.f;
  #pragma unroll
  for (int i=0;i<16;i++){ SE+=redE[i]; ST+=redT[i]; }
  float invE = 1.f/SE, invT = 1.f/ST;
  if (t < 500){
    int s = sq*500 + t;
    attE[t] = __expf(scE[b*SP+s]-ME)*invE;
    attT[t] = __expf(scT[b*SP+s]-MT)*invT;
  }
  __syncthreads();

  int sg = t>>8, h = t&255;
  const float* base = stat + ((size_t)(b*Sn + sq*500 + sg*125))*Hn + h;
  float aE=0.f, aT=0.f;
  #pragma unroll 4
  for (int i=0;i<125;i++){
    float a = base[(size_t)i*Hn];
    aE += attE[sg*125+i]*a;
    aT += attT[sg*125+i]*a;
  }
  pe[sg][h]=aE; pt[sg][h]=aT;
  __syncthreads();
  if (t < 256){
    float s0 = pe[0][t]+pe[1][t]+pe[2][t]+pe[3][t];
    ctxP[(((size_t)sq)*256 + t)*128 + b] = s0;
  } else if (t < 512){
    int h2 = t-256;
    float s1 = pt[0][h2]+pt[1][h2]+pt[2][h2]+pt[3][h2];
    ctxP[(((size_t)(2+sq))*256 + h2)*128 + b] = s1;
  }
}

// ---------------------------------------------------------------------------
// K3c: c2 matvec + fold c3. grid 128 x 512: group per row vr (0..511).
__global__ __launch_bounds__(512) void k3c_c2(
    const float* __restrict__ ctxP, const float* __restrict__ Wp,
    const float* __restrict__ c3,
    float* __restrict__ cE, float* __restrict__ cT){
  int t = threadIdx.x;
  int g = t >> 7, b = t & 127;
  int vr = blockIdx.x*4 + g;
  int var = vr >> 8, h = vr & 255;
  const float4* w4 = (const float4*)(Wp + (size_t)h*768 + 256);
  const float* x0 = ctxP + ((size_t)(var*2))*256*128;
  const float* x1 = ctxP + ((size_t)(var*2+1))*256*128;
  float acc = 0.f;
  #pragma unroll 2
  for (int kq=0; kq<64; kq++){
    float4 wv = w4[kq];
    #pragma unroll
    for (int e=0;e<4;e++){
      int k = kq*4+e;
      acc += (&wv.x)[e] * (x0[k*128+b] + x1[k*128+b]);
    }
  }
  (var ? cT : cE)[b*256 + h] = acc + c3[b*256 + h];
}

// ---------------------------------------------------------------------------
// K4: final reduction from Aptr (C-reg layout, coalesced). grid (16,128) x 256.
__global__ __launch_bounds__(256) void k4_final(
    const bf16* __restrict__ Aptr, const float* __restrict__ cE,
    const float* __restrict__ cT, const float* __restrict__ vp,
    float* __restrict__ out){
  __shared__ float pE[64], pT[64];
  int tid=threadIdx.x, w=tid>>6, l=tid&63;
  int st=blockIdx.x, b=blockIdx.y;
  int lm=l&15, q=l>>4;
  if (tid < 64){ pE[tid]=0.f; pT[tid]=0.f; }
  __syncthreads();
  const bf16* src = Aptr + ((size_t)(b*16 + st))*16384;
  float vj[4], ej[4], tj[4];
  #pragma unroll
  for (int j=0;j<4;j++){
    int hh = w*64 + j*16 + lm;
    vj[j]=vp[hh]; ej[j]=cE[b*256+hh]; tj[j]=cT[b*256+hh];
  }
  #pragma unroll
  for (int i=0;i<4;i++){
    #pragma unroll
    for (int r=0;r<4;r++){
      int slot = i*4 + r;
      bf16x4 v4 = *(const bf16x4*)(src + ((size_t)((slot*4 + w)*64 + l))*4);
      float pe=0.f, pt=0.f;
      #pragma unroll
      for (int j=0;j<4;j++){
        float a = (float)v4[j];
        pe += vj[j]*fast_tanh(a + ej[j]);
        pt += vj[j]*fast_tanh(a + tj[j]);
      }
      pe += __shfl_xor(pe,1); pt += __shfl_xor(pt,1);
      pe += __shfl_xor(pe,2); pt += __shfl_xor(pt,2);
      pe += __shfl_xor(pe,4); pt += __shfl_xor(pt,4);
      pe += __shfl_xor(pe,8); pt += __shfl_xor(pt,8);
      if (lm==0){
        atomicAdd(&pE[i*16 + q*4 + r], pe);
        atomicAdd(&pT[i*16 + q*4 + r], pt);
      }
    }
  }
  __syncthreads();
  if (tid < 64){
    int s = st*64 + tid;
    if (s < Sn) out[b*Sn + s] = 5.0f*pE[tid] + pT[tid];
  }
}

// ---------------------------------------------------------------------------
extern "C" void kernel_launch(void* const* d_in, const int* in_sizes, int n_in,
                              void* d_out, int out_size, void* d_ws, size_t ws_size,
                              hipStream_t stream){
  const float* stat = (const float*)d_in[0];
  const float* se   = (const float*)d_in[1];
  const float* dec  = (const float*)d_in[2];
  const float* tgt  = (const float*)d_in[3];
  const float* lhh  = (const float*)d_in[4];
  const float* Wih  = (const float*)d_in[5];
  const float* Whh  = (const float*)d_in[6];
  const float* bih  = (const float*)d_in[7];
  const float* bhh  = (const float*)d_in[8];
  const float* vEnc = (const float*)d_in[9];
  const float* WEnc = (const float*)d_in[10];
  const float* vTgt = (const float*)d_in[11];
  const float* WTgt = (const float*)d_in[12];
  const float* vPtr = (const float*)d_in[13];
  const float* WPtr = (const float*)d_in[14];
  float* out = (float*)d_out;

  char* wsp = (char*)d_ws;
  bf16*  Aptr = (bf16*)(wsp);                  // 67,108,864
  bf16*  Wcb  = (bf16*)(wsp + 67108864);       // 393,216
  float* xT   = (float*)(wsp + 67502080);      // 131,072
  float* hT   = (float*)(wsp + 67633152);      // 131,072
  float* tT   = (float*)(wsp + 67764224);      // 131,072
  float* sT   = (float*)(wsp + 67895296);      // 131,072
  float* hnT  = (float*)(wsp + 68026368);      // 131,072
  float* scE  = (float*)(wsp + 68157440);      // 524,288
  float* scT  = (float*)(wsp + 68681728);      // 524,288
  float* dEnc = (float*)(wsp + 69206016);      // 131,072
  float* dTgt = (float*)(wsp + 69337088);      // 131,072
  float* c3   = (float*)(wsp + 69468160);      // 131,072
  float* cE   = (float*)(wsp + 69599232);      // 131,072
  float* cT   = (float*)(wsp + 69730304);      // 131,072
  float* ctxP = (float*)(wsp + 69861376);      // 524,288 -> end 70,385,664

  hipLaunchKernelGGL(k0w, dim3(1280), dim3(256), 0, stream,
                     WEnc, WTgt, WPtr, Wcb, dec, lhh, tgt, se, xT, hT, tT, sT);
  hipLaunchKernelGGL(k1a_gru, dim3(64), dim3(512), 0, stream,
                     xT, hT, Wih, Whh, bih, bhh, out + Bn*Sn, hnT);
  hipLaunchKernelGGL(k1c_dots, dim3(192), dim3(512), 0, stream,
                     hnT, tT, sT, WEnc, WTgt, WPtr, dEnc, dTgt, c3);
  hipLaunchKernelGGL(k2_gemm, dim3(16, 128), dim3(256), 0, stream,
                     stat, Wcb, dEnc, dTgt, vEnc, vTgt, scE, scT, Aptr);
  hipLaunchKernelGGL(k3_ctx, dim3(128, 2), dim3(1024), 0, stream,
                     scE, scT, stat, ctxP);
  hipLaunchKernelGGL(k3c_c2, dim3(128), dim3(512), 0, stream,
                     ctxP, WPtr, c3, cE, cT);
  hipLaunchKernelGGL(k4_final, dim3(16, 128), dim3(256), 0, stream,
                     Aptr, cE, cT, vPtr, out);
}

// Round 6
// 444.548 us; speedup vs baseline: 1.3253x; 1.0312x over previous
//
#include <hip/hip_runtime.h>
#include <hip/hip_bf16.h>
#include <stdint.h>
#include <stddef.h>

#define Bn 128
#define Sn 1000
#define SP 1024
#define Hn 256

typedef __bf16 bf16;
typedef __bf16 bf16x8 __attribute__((ext_vector_type(8)));
typedef __bf16 bf16x4 __attribute__((ext_vector_type(4)));
typedef float  f32x16 __attribute__((ext_vector_type(16)));

typedef __attribute__((address_space(1))) const unsigned int* gas1;
typedef __attribute__((address_space(3))) unsigned int* las3;

__device__ __forceinline__ float fast_tanh(float x){
  return 1.0f - 2.0f / (__expf(2.0f * x) + 1.0f);
}
__device__ __forceinline__ float fast_sigmoid(float x){
  return 1.0f / (1.0f + __expf(-x));
}

// ---------------------------------------------------------------------------
// K0w: pack Wc (768x256 bf16) and transpose dec/lhh/tgt/se to [k][b].
__global__ void k0w(const float* __restrict__ We, const float* __restrict__ Wt,
                    const float* __restrict__ Wp, bf16* __restrict__ Wcb,
                    const float* __restrict__ dec, const float* __restrict__ lhh,
                    const float* __restrict__ tgt, const float* __restrict__ se,
                    float* __restrict__ xT, float* __restrict__ hT,
                    float* __restrict__ tT, float* __restrict__ sT){
  int blk = blockIdx.x, t = threadIdx.x;
  if (blk < 768){
    int tt = blk*256 + t;
    int r = tt >> 8, c = tt & 255;
    float val;
    if (r < 256)       val = We[r*512 + c];
    else if (r < 512)  val = Wt[(r-256)*512 + c];
    else               val = Wp[(r-512)*768 + c];
    Wcb[tt] = (bf16)val;
  } else {
    int idx = blk - 768;
    int a = idx >> 7, bb = idx & 127;
    const float* src = (a==0) ? dec : (a==1) ? lhh : (a==2) ? tgt : se;
    float* dst       = (a==0) ? xT  : (a==1) ? hT  : (a==2) ? tT  : sT;
    dst[t*128 + bb] = src[bb*256 + t];
  }
}

// ---------------------------------------------------------------------------
// K1a: fused GRU. grid 64 x 512 (group of 128 b-lanes per h).
__global__ __launch_bounds__(512) void k1a_gru(
    const float* __restrict__ xT, const float* __restrict__ hT,
    const float* __restrict__ Wih, const float* __restrict__ Whh,
    const float* __restrict__ bih, const float* __restrict__ bhh,
    float* __restrict__ out_hh, float* __restrict__ hnT){
  int t = threadIdx.x;
  int g = t >> 7, b = t & 127;
  int h = blockIdx.x*4 + g;
  const float4* wir = (const float4*)(Wih + (size_t)h*256);
  const float4* wiz = (const float4*)(Wih + (size_t)(256+h)*256);
  const float4* wig = (const float4*)(Wih + (size_t)(512+h)*256);
  const float4* whr = (const float4*)(Whh + (size_t)h*256);
  const float4* whz = (const float4*)(Whh + (size_t)(256+h)*256);
  const float4* whg = (const float4*)(Whh + (size_t)(512+h)*256);
  float air=0.f, aiz=0.f, aig=0.f, ahr=0.f, ahz=0.f, ahg=0.f;
  #pragma unroll 2
  for (int kq=0; kq<64; kq++){
    float4 vir = wir[kq], viz = wiz[kq], vig = wig[kq];
    float4 vhr = whr[kq], vhz = whz[kq], vhg = whg[kq];
    #pragma unroll
    for (int e=0;e<4;e++){
      int k = kq*4 + e;
      float xv = xT[k*128 + b];
      float hv = hT[k*128 + b];
      air += (&vir.x)[e]*xv; aiz += (&viz.x)[e]*xv; aig += (&vig.x)[e]*xv;
      ahr += (&vhr.x)[e]*hv; ahz += (&vhz.x)[e]*hv; ahg += (&vhg.x)[e]*hv;
    }
  }
  air += bih[h];      ahr += bhh[h];
  aiz += bih[256+h];  ahz += bhh[256+h];
  aig += bih[512+h];  ahg += bhh[512+h];
  float r = fast_sigmoid(air + ahr);
  float z = fast_sigmoid(aiz + ahz);
  float n = fast_tanh(aig + r*ahg);
  float hprev = hT[h*128 + b];
  float hnew = (1.f - z)*n + z*hprev;
  out_hh[b*256 + h] = hnew;
  hnT[h*128 + b] = hnew;
}

// ---------------------------------------------------------------------------
// K1c: d_enc/d_tgt/c3 dots. grid 192 x 512.
__global__ __launch_bounds__(512) void k1c_dots(
    const float* __restrict__ hnT, const float* __restrict__ tT,
    const float* __restrict__ sT,
    const float* __restrict__ We, const float* __restrict__ Wt,
    const float* __restrict__ Wp,
    float* __restrict__ dEnc, float* __restrict__ dTgt, float* __restrict__ c3){
  int t = threadIdx.x;
  int g = t >> 7, b = t & 127;
  int vr = blockIdx.x*4 + g;
  int var = vr >> 8, h = vr & 255;
  const float* wrow; const float* X; float* dst;
  if (var == 0)      { wrow = We + (size_t)h*512 + 256; X = hnT; dst = dEnc; }
  else if (var == 1) { wrow = Wt + (size_t)h*512 + 256; X = tT;  dst = dTgt; }
  else               { wrow = Wp + (size_t)h*768 + 512; X = sT;  dst = c3; }
  const float4* w4 = (const float4*)wrow;
  float acc = 0.f;
  #pragma unroll 2
  for (int kq=0; kq<64; kq++){
    float4 wv = w4[kq];
    #pragma unroll
    for (int e=0;e<4;e++)
      acc += (&wv.x)[e] * X[(kq*4+e)*128 + b];
  }
  dst[b*256 + h] = acc;
}

// ---------------------------------------------------------------------------
// K2: fused GEMM, 32x32x16 MFMA. Block: M=64, 512 thr = 8 waves (2M x 4N),
// wave tile 32M x 64N. A (fp32->bf16) staged once to 32 KB LDS; B per
// (phase,kt) 256N x 64K = 32 KB via global_load_lds. 3 phases (enc/tgt/ptr),
// 4 kt each -> 12 barrier-phases, 8 MFMA(32x32x16)/wave each.
__global__ __launch_bounds__(512) void k2_gemm(
    const float* __restrict__ stat, const bf16* __restrict__ Wcb,
    const float* __restrict__ dEnc, const float* __restrict__ dTgt,
    const float* __restrict__ vEnc, const float* __restrict__ vTgt,
    float* __restrict__ scE, float* __restrict__ scT, bf16* __restrict__ Aptr){
  __shared__ __align__(16) bf16 As[64*256];   // 32 KB, row stride 512 B
  __shared__ __align__(16) bf16 Bs[256*64];   // 32 KB, row stride 128 B
  __shared__ float pS[2][64];
  int tid = threadIdx.x, w = tid>>6, l = tid&63;
  int st = blockIdx.x, b = blockIdx.y;
  int wm = (w>>2)*32, wn = (w&3)*64;
  int l31 = l & 31, lh = l >> 5;
  if (tid < 128) pS[tid>>6][tid&63] = 0.f;

  // A stage: 8 float4/thread, each wave covers one full row per issue.
  #pragma unroll
  for (int is=0; is<8; is++){
    int fidx = is*512 + tid;
    int row = fidx >> 6, col4 = fidx & 63;
    int s = st*64 + row;
    float4 f = make_float4(0.f,0.f,0.f,0.f);
    if (s < Sn) f = ((const float4*)(stat + ((size_t)(b*Sn + s))*Hn))[col4];
    bf16x4 v;
    v[0]=(bf16)f.x; v[1]=(bf16)f.y; v[2]=(bf16)f.z; v[3]=(bf16)f.w;
    int c8 = col4 >> 1, half = col4 & 1;
    *(bf16x4*)(&As[row*256 + ((c8 ^ (row&7))<<3) + half*4]) = v;
  }

  for (int p=0; p<3; p++){
    f32x16 acc[2];
    #pragma unroll
    for (int j=0;j<2;j++)
      #pragma unroll
      for (int r=0;r<16;r++) acc[j][r] = 0.f;

    for (int kt=0; kt<4; kt++){
      __syncthreads();
      // stage B: 4 issues/thread; issue covers 8 rows x 128 B per wave.
      #pragma unroll
      for (int is=0; is<4; is++){
        int row = is*64 + w*8 + (l>>3);
        int gch = (l&7) ^ (row&7);
        __builtin_amdgcn_global_load_lds(
            (gas1)(Wcb + ((size_t)(p*256 + row))*256 + kt*64 + gch*8),
            (las3)(&Bs[(is*64 + w*8)*64]), 16, 0, 0);
      }
      __syncthreads();
      #pragma unroll
      for (int kc=0; kc<4; kc++){
        int rA = wm + l31;
        int ck = kt*8 + kc*2 + lh;
        bf16x8 af = *(const bf16x8*)(&As[rA*256 + ((ck ^ (rA&7))<<3)]);
        #pragma unroll
        for (int j=0;j<2;j++){
          int n = wn + j*32 + l31;
          int ckb = kc*2 + lh;
          bf16x8 bfv = *(const bf16x8*)(&Bs[n*64 + ((ckb ^ (n&7))<<3)]);
          acc[j] = __builtin_amdgcn_mfma_f32_32x32x16_bf16(af, bfv, acc[j], 0,0,0);
        }
      }
    }

    if (p < 2){
      const float* vv = p ? vTgt : vEnc;
      const float* db = (p ? dTgt : dEnc) + b*256;
      float vj[2], dj[2];
      #pragma unroll
      for (int j=0;j<2;j++){
        int hh = wn + j*32 + l31;
        vj[j] = vv[hh]; dj[j] = db[hh];
      }
      #pragma unroll
      for (int r=0;r<16;r++){
        float pp = vj[0]*fast_tanh(acc[0][r] + dj[0])
                 + vj[1]*fast_tanh(acc[1][r] + dj[1]);
        pp += __shfl_xor(pp,1); pp += __shfl_xor(pp,2);
        pp += __shfl_xor(pp,4); pp += __shfl_xor(pp,8); pp += __shfl_xor(pp,16);
        if (l31 == 0){
          int row = wm + (r&3) + 8*(r>>2) + 4*lh;
          atomicAdd(&pS[p][row], pp);
        }
      }
    } else {
      bf16* dst = Aptr + ((size_t)(b*16 + st))*16384;
      #pragma unroll
      for (int j=0;j<2;j++){
        #pragma unroll
        for (int q4=0;q4<4;q4++){
          bf16x4 v4;
          #pragma unroll
          for (int rr=0;rr<4;rr++) v4[rr] = (bf16)acc[j][q4*4+rr];
          int slot = w*8 + j*4 + q4;
          *(bf16x4*)(dst + ((size_t)(slot*64 + l))*4) = v4;
        }
      }
    }
  }
  __syncthreads();
  if (tid < 64)        scE[b*SP + st*64 + tid]      = pS[0][tid];
  else if (tid < 128)  scT[b*SP + st*64 + tid-64]   = pS[1][tid-64];
}

// ---------------------------------------------------------------------------
// K3: softmax (full S, both branches) + context over 500 rows, float4 cols.
// grid (128 b, 2 sg) x 1024. Partials atomicAdd into ctxG [var][b][h] (zeroed).
__global__ __launch_bounds__(1024) void k3_ctx(
    const float* __restrict__ scE, const float* __restrict__ scT,
    const float* __restrict__ stat, float* __restrict__ ctxG){
  __shared__ float attE[500], attT[500];
  __shared__ float redE[16], redT[16];
  __shared__ float4 pe4[16][64], pt4[16][64];
  int b = blockIdx.x, sg = blockIdx.y, t = threadIdx.x;
  int wid = t>>6, ln = t&63;

  float vE = (t < Sn) ? scE[b*SP + t] : -1e30f;
  float vT = (t < Sn) ? scT[b*SP + t] : -1e30f;
  float mE = vE, mT = vT;
  #pragma unroll
  for (int o=1;o<64;o<<=1){ mE=fmaxf(mE,__shfl_xor(mE,o)); mT=fmaxf(mT,__shfl_xor(mT,o)); }
  if (ln==0){ redE[wid]=mE; redT[wid]=mT; }
  __syncthreads();
  float ME=-1e30f, MT=-1e30f;
  #pragma unroll
  for (int i=0;i<16;i++){ ME=fmaxf(ME,redE[i]); MT=fmaxf(MT,redT[i]); }
  __syncthreads();
  float eE = (t < Sn) ? __expf(vE-ME) : 0.f;
  float eT = (t < Sn) ? __expf(vT-MT) : 0.f;
  float sE=eE, sT=eT;
  #pragma unroll
  for (int o=1;o<64;o<<=1){ sE+=__shfl_xor(sE,o); sT+=__shfl_xor(sT,o); }
  if (ln==0){ redE[wid]=sE; redT[wid]=sT; }
  __syncthreads();
  float SE=0.f, ST=0.f;
  #pragma unroll
  for (int i=0;i<16;i++){ SE+=redE[i]; ST+=redT[i]; }
  float invE = 1.f/SE, invT = 1.f/ST;
  if (t < 500){
    int s = sg*500 + t;
    attE[t] = __expf(scE[b*SP+s]-ME)*invE;
    attT[t] = __expf(scT[b*SP+s]-MT)*invT;
  }
  __syncthreads();

  // context: h4 = t&63 (float4 col), rg = t>>6 (16 row groups of 32)
  int h4 = t & 63, rg = t >> 6;
  float4 aE = make_float4(0.f,0.f,0.f,0.f), aT = aE;
  int nrows = (rg == 15) ? 20 : 32;   // 15*32=480, 500-480=20
  const float4* base = (const float4*)(stat + ((size_t)(b*Sn + sg*500 + rg*32))*Hn) + h4;
  #pragma unroll 4
  for (int i=0;i<nrows;i++){
    float4 f = base[(size_t)i*64];
    float wE = attE[rg*32 + i], wT = attT[rg*32 + i];
    aE.x += wE*f.x; aE.y += wE*f.y; aE.z += wE*f.z; aE.w += wE*f.w;
    aT.x += wT*f.x; aT.y += wT*f.y; aT.z += wT*f.z; aT.w += wT*f.w;
  }
  pe4[rg][h4] = aE; pt4[rg][h4] = aT;
  __syncthreads();
  if (t < 64){
    float4 s = make_float4(0.f,0.f,0.f,0.f);
    #pragma unroll
    for (int i=0;i<16;i++){
      float4 p = pe4[i][t];
      s.x+=p.x; s.y+=p.y; s.z+=p.z; s.w+=p.w;
    }
    atomicAdd(&ctxG[b*256 + t*4 + 0], s.x);
    atomicAdd(&ctxG[b*256 + t*4 + 1], s.y);
    atomicAdd(&ctxG[b*256 + t*4 + 2], s.z);
    atomicAdd(&ctxG[b*256 + t*4 + 3], s.w);
  } else if (t < 128){
    int h = t - 64;
    float4 s = make_float4(0.f,0.f,0.f,0.f);
    #pragma unroll
    for (int i=0;i<16;i++){
      float4 p = pt4[i][h];
      s.x+=p.x; s.y+=p.y; s.z+=p.z; s.w+=p.w;
    }
    atomicAdd(&ctxG[32768 + b*256 + h*4 + 0], s.x);
    atomicAdd(&ctxG[32768 + b*256 + h*4 + 1], s.y);
    atomicAdd(&ctxG[32768 + b*256 + h*4 + 2], s.z);
    atomicAdd(&ctxG[32768 + b*256 + h*4 + 3], s.w);
  }
}

// ---------------------------------------------------------------------------
// K3c: c2 = Wptr[:,H:2H]@ctx + c3. grid 128 (b) x 512 (2 var x 256 h).
__global__ __launch_bounds__(512) void k3c_c2(
    const float* __restrict__ ctxG, const float* __restrict__ Wp,
    const float* __restrict__ c3,
    float* __restrict__ cE, float* __restrict__ cT){
  __shared__ __align__(16) float ctxL[512];
  int b = blockIdx.x, t = threadIdx.x;
  ctxL[t] = ctxG[(t>>8)*32768 + b*256 + (t&255)];
  __syncthreads();
  int var = t >> 8, h = t & 255;
  const float4* w4 = (const float4*)(Wp + (size_t)h*768 + 256);
  const float4* cv = (const float4*)(&ctxL[var*256]);
  float acc = 0.f;
  #pragma unroll 4
  for (int k=0;k<64;k++){
    float4 wv = w4[k], xv = cv[k];
    acc += wv.x*xv.x + wv.y*xv.y + wv.z*xv.z + wv.w*xv.w;
  }
  (var ? cT : cE)[b*256 + h] = acc + c3[b*256 + h];
}

// ---------------------------------------------------------------------------
// K4: final reduction from Aptr (C-layout, coalesced). grid (16,128) x 512.
__global__ __launch_bounds__(512) void k4_final(
    const bf16* __restrict__ Aptr, const float* __restrict__ cE,
    const float* __restrict__ cT, const float* __restrict__ vp,
    float* __restrict__ out){
  __shared__ float pE[64], pT[64];
  int tid=threadIdx.x, w=tid>>6, l=tid&63;
  int st=blockIdx.x, b=blockIdx.y;
  int wm=(w>>2)*32, wn=(w&3)*64;
  int l31=l&31, lh=l>>5;
  if (tid < 128){ (tid<64 ? pE : pT)[tid&63] = 0.f; }
  __syncthreads();
  const bf16* src = Aptr + ((size_t)(b*16 + st))*16384;
  float vj[2], ej[2], tj[2];
  #pragma unroll
  for (int j=0;j<2;j++){
    int hh = wn + j*32 + l31;
    vj[j]=vp[hh]; ej[j]=cE[b*256+hh]; tj[j]=cT[b*256+hh];
  }
  float peR[16], ptR[16];
  #pragma unroll
  for (int r=0;r<16;r++){ peR[r]=0.f; ptR[r]=0.f; }
  #pragma unroll
  for (int j=0;j<2;j++){
    #pragma unroll
    for (int q4=0;q4<4;q4++){
      int slot = w*8 + j*4 + q4;
      bf16x4 v4 = *(const bf16x4*)(src + ((size_t)(slot*64 + l))*4);
      #pragma unroll
      for (int rr=0;rr<4;rr++){
        float a = (float)v4[rr];
        peR[q4*4+rr] += vj[j]*fast_tanh(a + ej[j]);
        ptR[q4*4+rr] += vj[j]*fast_tanh(a + tj[j]);
      }
    }
  }
  #pragma unroll
  for (int r=0;r<16;r++){
    float pe = peR[r], pt = ptR[r];
    pe += __shfl_xor(pe,1); pt += __shfl_xor(pt,1);
    pe += __shfl_xor(pe,2); pt += __shfl_xor(pt,2);
    pe += __shfl_xor(pe,4); pt += __shfl_xor(pt,4);
    pe += __shfl_xor(pe,8); pt += __shfl_xor(pt,8);
    pe += __shfl_xor(pe,16); pt += __shfl_xor(pt,16);
    if (l31 == 0){
      int row = wm + (r&3) + 8*(r>>2) + 4*lh;
      atomicAdd(&pE[row], pe);
      atomicAdd(&pT[row], pt);
    }
  }
  __syncthreads();
  if (tid < 64){
    int s = st*64 + tid;
    if (s < Sn) out[b*Sn + s] = 5.0f*pE[tid] + pT[tid];
  }
}

// ---------------------------------------------------------------------------
extern "C" void kernel_launch(void* const* d_in, const int* in_sizes, int n_in,
                              void* d_out, int out_size, void* d_ws, size_t ws_size,
                              hipStream_t stream){
  const float* stat = (const float*)d_in[0];
  const float* se   = (const float*)d_in[1];
  const float* dec  = (const float*)d_in[2];
  const float* tgt  = (const float*)d_in[3];
  const float* lhh  = (const float*)d_in[4];
  const float* Wih  = (const float*)d_in[5];
  const float* Whh  = (const float*)d_in[6];
  const float* bih  = (const float*)d_in[7];
  const float* bhh  = (const float*)d_in[8];
  const float* vEnc = (const float*)d_in[9];
  const float* WEnc = (const float*)d_in[10];
  const float* vTgt = (const float*)d_in[11];
  const float* WTgt = (const float*)d_in[12];
  const float* vPtr = (const float*)d_in[13];
  const float* WPtr = (const float*)d_in[14];
  float* out = (float*)d_out;

  char* wsp = (char*)d_ws;
  bf16*  Aptr = (bf16*)(wsp);                  // 67,108,864
  bf16*  Wcb  = (bf16*)(wsp + 67108864);       // 393,216
  float* xT   = (float*)(wsp + 67502080);      // 131,072
  float* hT   = (float*)(wsp + 67633152);      // 131,072
  float* tT   = (float*)(wsp + 67764224);      // 131,072
  float* sT   = (float*)(wsp + 67895296);      // 131,072
  float* hnT  = (float*)(wsp + 68026368);      // 131,072
  float* scE  = (float*)(wsp + 68157440);      // 524,288
  float* scT  = (float*)(wsp + 68681728);      // 524,288
  float* dEnc = (float*)(wsp + 69206016);      // 131,072
  float* dTgt = (float*)(wsp + 69337088);      // 131,072
  float* c3   = (float*)(wsp + 69468160);      // 131,072
  float* cE   = (float*)(wsp + 69599232);      // 131,072
  float* cT   = (float*)(wsp + 69730304);      // 131,072
  float* ctxG = (float*)(wsp + 69861376);      // 262,144 -> end 70,123,520

  hipMemsetAsync(ctxG, 0, 262144, stream);
  hipLaunchKernelGGL(k0w, dim3(1280), dim3(256), 0, stream,
                     WEnc, WTgt, WPtr, Wcb, dec, lhh, tgt, se, xT, hT, tT, sT);
  hipLaunchKernelGGL(k1a_gru, dim3(64), dim3(512), 0, stream,
                     xT, hT, Wih, Whh, bih, bhh, out + Bn*Sn, hnT);
  hipLaunchKernelGGL(k1c_dots, dim3(192), dim3(512), 0, stream,
                     hnT, tT, sT, WEnc, WTgt, WPtr, dEnc, dTgt, c3);
  hipLaunchKernelGGL(k2_gemm, dim3(16, 128), dim3(512), 0, stream,
                     stat, Wcb, dEnc, dTgt, vEnc, vTgt, scE, scT, Aptr);
  hipLaunchKernelGGL(k3_ctx, dim3(128, 2), dim3(1024), 0, stream,
                     scE, scT, stat, ctxG);
  hipLaunchKernelGGL(k3c_c2, dim3(128), dim3(512), 0, stream,
                     ctxG, WPtr, c3, cE, cT);
  hipLaunchKernelGGL(k4_final, dim3(16, 128), dim3(512), 0, stream,
                     Aptr, cE, cT, vPtr, out);
}